// Round 1
// baseline (149.485 us; speedup 1.0000x reference)
//
#include <hip/hip_runtime.h>
#include <math.h>

// Problem constants (fixed by setup_inputs)
//   h: (32, 512, 320) f32, a_link/b_link: (256, 64) f32, rollout: 1 (unused)
// Outputs: A_out (32,512,512) f32  then probs (32,) f32, concatenated.
#define BATCH   32
#define NPTS    512
#define FDIM    320
#define FOBS    256
#define DK      64
#define MROWS   (BATCH * NPTS)            // 16384
#define A_ELEMS ((size_t)BATCH * NPTS * NPTS)  // 8388608

// ---------------------------------------------------------------------------
// K1: [h_i | h_j] (16384 x 128) = h[:, :256] (16384 x 256, ld=320) @ W(256x128)
//     where W = [a_link | b_link]. BM=64, BN=128, BK=32; 256 threads; 4x8 acc.
// ---------------------------------------------------------------------------
__global__ __launch_bounds__(256) void k1_proj(const float* __restrict__ h,
                                               const float* __restrict__ al,
                                               const float* __restrict__ bl,
                                               float* __restrict__ hi,
                                               float* __restrict__ hj) {
    __shared__ float a_lds[64][36];    // 64 rows x 32 k (pad 36 keeps 16B align)
    __shared__ float w_lds[32][132];   // 32 k x 128 cols (pad 132, 16B align)

    const int t  = threadIdx.x;
    const int m0 = blockIdx.x * 64;
    const int ty = t >> 4, tx = t & 15;   // 16 x 16 thread grid

    float acc[4][8];
#pragma unroll
    for (int i = 0; i < 4; ++i)
#pragma unroll
        for (int j = 0; j < 8; ++j) acc[i][j] = 0.f;

    for (int k0 = 0; k0 < FOBS; k0 += 32) {
        __syncthreads();
        // stage A tile: 64x32 f32 = 512 float4, 2 per thread
#pragma unroll
        for (int s = 0; s < 2; ++s) {
            int id = t + s * 256;
            int r = id >> 3, q = id & 7;
            float4 v = *reinterpret_cast<const float4*>(
                &h[(size_t)(m0 + r) * FDIM + k0 + q * 4]);
            *reinterpret_cast<float4*>(&a_lds[r][q * 4]) = v;
        }
        // stage W tile: 32x128 f32 = 1024 float4, 4 per thread
#pragma unroll
        for (int s = 0; s < 4; ++s) {
            int id = t + s * 256;
            int kk = id >> 5, ch = id & 31;
            const float* src = (ch < 16) ? &al[(size_t)(k0 + kk) * 64 + ch * 4]
                                         : &bl[(size_t)(k0 + kk) * 64 + (ch - 16) * 4];
            float4 v = *reinterpret_cast<const float4*>(src);
            *reinterpret_cast<float4*>(&w_lds[kk][ch * 4]) = v;
        }
        __syncthreads();

#pragma unroll
        for (int kk = 0; kk < 32; kk += 4) {
            float a_k[4][4];   // [row i][q]
#pragma unroll
            for (int i = 0; i < 4; ++i) {
                float4 v = *reinterpret_cast<const float4*>(&a_lds[ty * 4 + i][kk]);
                a_k[i][0] = v.x; a_k[i][1] = v.y; a_k[i][2] = v.z; a_k[i][3] = v.w;
            }
#pragma unroll
            for (int q = 0; q < 4; ++q) {
                float4 w0 = *reinterpret_cast<const float4*>(&w_lds[kk + q][tx * 8]);
                float4 w1 = *reinterpret_cast<const float4*>(&w_lds[kk + q][tx * 8 + 4]);
                float wv[8] = {w0.x, w0.y, w0.z, w0.w, w1.x, w1.y, w1.z, w1.w};
#pragma unroll
                for (int i = 0; i < 4; ++i) {
                    float a = a_k[i][q];
#pragma unroll
                    for (int j = 0; j < 8; ++j)
                        acc[i][j] = fmaf(a, wv[j], acc[i][j]);
                }
            }
        }
    }

    // epilogue: cols 0..63 -> hi, 64..127 -> hj
    const int c = tx * 8;
    float* dst = (c < 64) ? (hi + c) : (hj + (c - 64));
#pragma unroll
    for (int i = 0; i < 4; ++i) {
        size_t row = (size_t)(m0 + ty * 4 + i);
        float4 v0 = make_float4(acc[i][0], acc[i][1], acc[i][2], acc[i][3]);
        float4 v1 = make_float4(acc[i][4], acc[i][5], acc[i][6], acc[i][7]);
        *reinterpret_cast<float4*>(&dst[row * 64])     = v0;
        *reinterpret_cast<float4*>(&dst[row * 64 + 4]) = v1;
    }
}

// ---------------------------------------------------------------------------
// K2: per (b, 64x64 tile): logits = hi_tile @ hj_tile^T / 8; fused epilogue:
//     A = (logits > 0) with diag forced to 1; partial logp sum per tile.
// ---------------------------------------------------------------------------
__global__ __launch_bounds__(256) void k2_logits(const float* __restrict__ hi,
                                                 const float* __restrict__ hj,
                                                 float* __restrict__ Aout,
                                                 float* __restrict__ partials) {
    __shared__ float hi_lds[64][68];   // [row][k]
    __shared__ float hjT[64][68];      // [k][col]  (transposed)
    __shared__ float red[4];

    const int t  = threadIdx.x;
    const int jt = blockIdx.x, it = blockIdx.y, b = blockIdx.z;
    const int i0 = it * 64, j0 = jt * 64;

    const float* hib = hi + ((size_t)b * NPTS + i0) * DK;
    const float* hjb = hj + ((size_t)b * NPTS + j0) * DK;

    // stage: 1024 float4 each, 4 per thread
#pragma unroll
    for (int s = 0; s < 4; ++s) {
        int id = t + s * 256;
        int row = id >> 4, ch = id & 15;
        float4 v = *reinterpret_cast<const float4*>(&hib[(size_t)row * DK + ch * 4]);
        *reinterpret_cast<float4*>(&hi_lds[row][ch * 4]) = v;
        float4 u = *reinterpret_cast<const float4*>(&hjb[(size_t)row * DK + ch * 4]);
        int kk = ch * 4;
        hjT[kk + 0][row] = u.x; hjT[kk + 1][row] = u.y;
        hjT[kk + 2][row] = u.z; hjT[kk + 3][row] = u.w;
    }
    __syncthreads();

    const int ty = t >> 4, tx = t & 15;
    const int r0 = ty * 4, c0 = tx * 4;

    float acc[4][4];
#pragma unroll
    for (int i = 0; i < 4; ++i)
#pragma unroll
        for (int j = 0; j < 4; ++j) acc[i][j] = 0.f;

#pragma unroll
    for (int kk = 0; kk < DK; kk += 4) {
        float a_k[4][4];
#pragma unroll
        for (int i = 0; i < 4; ++i) {
            float4 v = *reinterpret_cast<const float4*>(&hi_lds[r0 + i][kk]);
            a_k[i][0] = v.x; a_k[i][1] = v.y; a_k[i][2] = v.z; a_k[i][3] = v.w;
        }
#pragma unroll
        for (int q = 0; q < 4; ++q) {
            float4 w = *reinterpret_cast<const float4*>(&hjT[kk + q][c0]);
            float wv[4] = {w.x, w.y, w.z, w.w};
#pragma unroll
            for (int i = 0; i < 4; ++i)
#pragma unroll
                for (int j = 0; j < 4; ++j)
                    acc[i][j] = fmaf(a_k[i][q], wv[j], acc[i][j]);
        }
    }

    // epilogue
    float lsum = 0.f;
    float* Ab = Aout + (((size_t)b * NPTS + i0)) * NPTS + j0;
#pragma unroll
    for (int i = 0; i < 4; ++i) {
        int gi = r0 + i;
        float ov[4];
#pragma unroll
        for (int j = 0; j < 4; ++j) {
            float x = acc[i][j] * 0.125f;   // / sqrt(64), tau = 1
            bool diag = (i0 + gi) == (j0 + c0 + j);
            if (diag) {
                ov[j] = 1.f;
            } else {
                ov[j] = (x > 0.f) ? 1.f : 0.f;
                float ax  = fabsf(x);
                float e   = expf(-ax);
                float sel = 1.0f / (1.0f + e);   // = max(y, 1-y)
                lsum += logf(sel + 1e-8f);
            }
        }
        float4 vo = make_float4(ov[0], ov[1], ov[2], ov[3]);
        *reinterpret_cast<float4*>(&Ab[(size_t)gi * NPTS + c0]) = vo;
    }

    // deterministic block reduction of lsum
#pragma unroll
    for (int off = 32; off > 0; off >>= 1) lsum += __shfl_down(lsum, off);
    const int lane = t & 63, w = t >> 6;
    if (lane == 0) red[w] = lsum;
    __syncthreads();
    if (t == 0) {
        float s = (red[0] + red[1]) + (red[2] + red[3]);
        partials[(size_t)b * 64 + it * 8 + jt] = s;
    }
}

// ---------------------------------------------------------------------------
// K3: probs[b] = sum of 64 tile partials (deterministic wave reduction)
// ---------------------------------------------------------------------------
__global__ __launch_bounds__(64) void k3_reduce(const float* __restrict__ partials,
                                                float* __restrict__ probs) {
    int b = blockIdx.x;
    float s = partials[(size_t)b * 64 + threadIdx.x];
#pragma unroll
    for (int off = 32; off > 0; off >>= 1) s += __shfl_down(s, off);
    if (threadIdx.x == 0) probs[b] = s;
}

extern "C" void kernel_launch(void* const* d_in, const int* in_sizes, int n_in,
                              void* d_out, int out_size, void* d_ws, size_t ws_size,
                              hipStream_t stream) {
    const float* h  = (const float*)d_in[0];
    const float* al = (const float*)d_in[1];
    const float* bl = (const float*)d_in[2];
    float* out = (float*)d_out;

    float* hi       = (float*)d_ws;                       // 16384*64 f32
    float* hj       = hi + (size_t)MROWS * DK;            // 16384*64 f32
    float* partials = hj + (size_t)MROWS * DK;            // 32*64 f32

    k1_proj<<<MROWS / 64, 256, 0, stream>>>(h, al, bl, hi, hj);

    dim3 g2(NPTS / 64, NPTS / 64, BATCH);
    k2_logits<<<g2, 256, 0, stream>>>(hi, hj, out, partials);

    k3_reduce<<<BATCH, 64, 0, stream>>>(partials, out + A_ELEMS);
}

// Round 2
// 62.527 us; speedup vs baseline: 2.3907x; 2.3907x over previous
//
#include <hip/hip_runtime.h>
#include <math.h>

// Problem constants (fixed by setup_inputs)
//   h: (32, 512, 320) f32, a_link/b_link: (256, 64) f32, rollout: 1 (unused)
// Outputs: A_out (32,512,512) f32  then probs (32,) f32, concatenated.
#define BATCH   32
#define NPTS    512
#define FDIM    320
#define FOBS    256
#define DK      64
#define MROWS   (BATCH * NPTS)            // 16384
#define A_ELEMS ((size_t)BATCH * NPTS * NPTS)  // 8388608

// ---------------------------------------------------------------------------
// K1: [h_i | h_j] (16384 x 128) = h[:, :256] (16384 x 256, ld=320) @ W(256x128)
//     where W = [a_link | b_link]. BM=64, BN=128, BK=32; 256 threads; 4x8 acc.
// ---------------------------------------------------------------------------
__global__ __launch_bounds__(256) void k1_proj(const float* __restrict__ h,
                                               const float* __restrict__ al,
                                               const float* __restrict__ bl,
                                               float* __restrict__ hi,
                                               float* __restrict__ hj) {
    __shared__ float a_lds[64][36];    // 64 rows x 32 k (pad 36 keeps 16B align)
    __shared__ float w_lds[32][132];   // 32 k x 128 cols (pad 132, 16B align)

    const int t  = threadIdx.x;
    const int m0 = blockIdx.x * 64;
    const int ty = t >> 4, tx = t & 15;   // 16 x 16 thread grid

    float acc[4][8];
#pragma unroll
    for (int i = 0; i < 4; ++i)
#pragma unroll
        for (int j = 0; j < 8; ++j) acc[i][j] = 0.f;

    for (int k0 = 0; k0 < FOBS; k0 += 32) {
        __syncthreads();
        // stage A tile: 64x32 f32 = 512 float4, 2 per thread
#pragma unroll
        for (int s = 0; s < 2; ++s) {
            int id = t + s * 256;
            int r = id >> 3, q = id & 7;
            float4 v = *reinterpret_cast<const float4*>(
                &h[(size_t)(m0 + r) * FDIM + k0 + q * 4]);
            *reinterpret_cast<float4*>(&a_lds[r][q * 4]) = v;
        }
        // stage W tile: 32x128 f32 = 1024 float4, 4 per thread
#pragma unroll
        for (int s = 0; s < 4; ++s) {
            int id = t + s * 256;
            int kk = id >> 5, ch = id & 31;
            const float* src = (ch < 16) ? &al[(size_t)(k0 + kk) * 64 + ch * 4]
                                         : &bl[(size_t)(k0 + kk) * 64 + (ch - 16) * 4];
            float4 v = *reinterpret_cast<const float4*>(src);
            *reinterpret_cast<float4*>(&w_lds[kk][ch * 4]) = v;
        }
        __syncthreads();

#pragma unroll 2
        for (int kk = 0; kk < 32; kk += 4) {
            float a_k[4][4];   // [row i][q]
#pragma unroll
            for (int i = 0; i < 4; ++i) {
                float4 v = *reinterpret_cast<const float4*>(&a_lds[ty * 4 + i][kk]);
                a_k[i][0] = v.x; a_k[i][1] = v.y; a_k[i][2] = v.z; a_k[i][3] = v.w;
            }
#pragma unroll
            for (int q = 0; q < 4; ++q) {
                float4 w0 = *reinterpret_cast<const float4*>(&w_lds[kk + q][tx * 8]);
                float4 w1 = *reinterpret_cast<const float4*>(&w_lds[kk + q][tx * 8 + 4]);
                float wv[8] = {w0.x, w0.y, w0.z, w0.w, w1.x, w1.y, w1.z, w1.w};
#pragma unroll
                for (int i = 0; i < 4; ++i) {
                    float a = a_k[i][q];
#pragma unroll
                    for (int j = 0; j < 8; ++j)
                        acc[i][j] = fmaf(a, wv[j], acc[i][j]);
                }
            }
        }
    }

    // epilogue: cols 0..63 -> hi, 64..127 -> hj
    const int c = tx * 8;
    float* dst = (c < 64) ? (hi + c) : (hj + (c - 64));
#pragma unroll
    for (int i = 0; i < 4; ++i) {
        size_t row = (size_t)(m0 + ty * 4 + i);
        float4 v0 = make_float4(acc[i][0], acc[i][1], acc[i][2], acc[i][3]);
        float4 v1 = make_float4(acc[i][4], acc[i][5], acc[i][6], acc[i][7]);
        *reinterpret_cast<float4*>(&dst[row * 64])     = v0;
        *reinterpret_cast<float4*>(&dst[row * 64 + 4]) = v1;
    }
}

// ---------------------------------------------------------------------------
// K2: per (b, 64x64 tile): logits = hi_tile @ hj_tile^T / 8; fused epilogue:
//     A = (logits > 0) with diag forced to 1; partial logp sum per tile.
//     launch_bounds(256,4): cap VGPR at 128 -> 4 blocks/CU (LDS 35KB) -> 50% occ.
// ---------------------------------------------------------------------------
__global__ __launch_bounds__(256, 4) void k2_logits(const float* __restrict__ hi,
                                                    const float* __restrict__ hj,
                                                    float* __restrict__ Aout,
                                                    float* __restrict__ partials) {
    __shared__ float hi_lds[64][68];   // [row][k]
    __shared__ float hjT[64][68];      // [k][col]  (transposed)
    __shared__ float red[4];

    const int t  = threadIdx.x;
    const int jt = blockIdx.x, it = blockIdx.y, b = blockIdx.z;
    const int i0 = it * 64, j0 = jt * 64;

    const float* hib = hi + ((size_t)b * NPTS + i0) * DK;
    const float* hjb = hj + ((size_t)b * NPTS + j0) * DK;

    // stage: 1024 float4 each, 4 per thread
#pragma unroll
    for (int s = 0; s < 4; ++s) {
        int id = t + s * 256;
        int row = id >> 4, ch = id & 15;
        float4 v = *reinterpret_cast<const float4*>(&hib[(size_t)row * DK + ch * 4]);
        *reinterpret_cast<float4*>(&hi_lds[row][ch * 4]) = v;
        float4 u = *reinterpret_cast<const float4*>(&hjb[(size_t)row * DK + ch * 4]);
        int kk = ch * 4;
        hjT[kk + 0][row] = u.x; hjT[kk + 1][row] = u.y;
        hjT[kk + 2][row] = u.z; hjT[kk + 3][row] = u.w;
    }
    __syncthreads();

    const int ty = t >> 4, tx = t & 15;
    const int r0 = ty * 4, c0 = tx * 4;

    float acc[4][4];
#pragma unroll
    for (int i = 0; i < 4; ++i)
#pragma unroll
        for (int j = 0; j < 4; ++j) acc[i][j] = 0.f;

#pragma unroll 2
    for (int kk = 0; kk < DK; kk += 4) {
        float a_k[4][4];
#pragma unroll
        for (int i = 0; i < 4; ++i) {
            float4 v = *reinterpret_cast<const float4*>(&hi_lds[r0 + i][kk]);
            a_k[i][0] = v.x; a_k[i][1] = v.y; a_k[i][2] = v.z; a_k[i][3] = v.w;
        }
#pragma unroll
        for (int q = 0; q < 4; ++q) {
            float4 w = *reinterpret_cast<const float4*>(&hjT[kk + q][c0]);
            float wv[4] = {w.x, w.y, w.z, w.w};
#pragma unroll
            for (int i = 0; i < 4; ++i)
#pragma unroll
                for (int j = 0; j < 4; ++j)
                    acc[i][j] = fmaf(a_k[i][q], wv[j], acc[i][j]);
        }
    }

    // epilogue: A = (x>0), diag = 1; logp = -log(1+exp(-|x|)) summed off-diag
    float lsum = 0.f;
    float* Ab = Aout + ((size_t)b * NPTS + i0) * NPTS + j0;
    const bool diag_block = (it == jt);
#pragma unroll
    for (int i = 0; i < 4; ++i) {
        int gi = r0 + i;
        float ov[4];
#pragma unroll
        for (int j = 0; j < 4; ++j) {
            float x  = acc[i][j] * 0.125f;   // / sqrt(64), tau = 1
            float ax = fabsf(x);
            float e  = __expf(-ax);          // fast v_exp path
            float l  = __logf(1.0f + e);     // fast v_log path; -logp
            bool diag = diag_block && (gi == c0 + j);
            ov[j] = diag ? 1.f : ((x > 0.f) ? 1.f : 0.f);
            lsum -= diag ? 0.f : l;
        }
        float4 vo = make_float4(ov[0], ov[1], ov[2], ov[3]);
        *reinterpret_cast<float4*>(&Ab[(size_t)gi * NPTS + c0]) = vo;
    }

    // deterministic block reduction of lsum
#pragma unroll
    for (int off = 32; off > 0; off >>= 1) lsum += __shfl_down(lsum, off);
    const int lane = t & 63, w = t >> 6;
    if (lane == 0) red[w] = lsum;
    __syncthreads();
    if (t == 0) {
        float s = (red[0] + red[1]) + (red[2] + red[3]);
        partials[(size_t)b * 64 + it * 8 + jt] = s;
    }
}

// ---------------------------------------------------------------------------
// K3: probs[b] = sum of 64 tile partials (deterministic wave reduction)
// ---------------------------------------------------------------------------
__global__ __launch_bounds__(64) void k3_reduce(const float* __restrict__ partials,
                                                float* __restrict__ probs) {
    int b = blockIdx.x;
    float s = partials[(size_t)b * 64 + threadIdx.x];
#pragma unroll
    for (int off = 32; off > 0; off >>= 1) s += __shfl_down(s, off);
    if (threadIdx.x == 0) probs[b] = s;
}

extern "C" void kernel_launch(void* const* d_in, const int* in_sizes, int n_in,
                              void* d_out, int out_size, void* d_ws, size_t ws_size,
                              hipStream_t stream) {
    const float* h  = (const float*)d_in[0];
    const float* al = (const float*)d_in[1];
    const float* bl = (const float*)d_in[2];
    float* out = (float*)d_out;

    float* hi       = (float*)d_ws;                       // 16384*64 f32
    float* hj       = hi + (size_t)MROWS * DK;            // 16384*64 f32
    float* partials = hj + (size_t)MROWS * DK;            // 32*64 f32

    k1_proj<<<MROWS / 64, 256, 0, stream>>>(h, al, bl, hi, hj);

    dim3 g2(NPTS / 64, NPTS / 64, BATCH);
    k2_logits<<<g2, 256, 0, stream>>>(hi, hj, out, partials);

    k3_reduce<<<BATCH, 64, 0, stream>>>(partials, out + A_ELEMS);
}

// Round 3
// 44.810 us; speedup vs baseline: 3.3360x; 1.3954x over previous
//
#include <hip/hip_runtime.h>
#include <math.h>

// Problem constants (fixed by setup_inputs)
//   h: (32, 512, 320) f32, a_link/b_link: (256, 64) f32, rollout: 1 (unused)
// Outputs: A_out (32,512,512) f32  then probs (32,) f32, concatenated.
#define BATCH   32
#define NPTS    512
#define FDIM    320
#define FOBS    256
#define DK      64
#define MROWS   (BATCH * NPTS)            // 16384
#define A_ELEMS ((size_t)BATCH * NPTS * NPTS)  // 8388608

typedef __bf16  bf16x8 __attribute__((ext_vector_type(8)));
typedef float   f32x4  __attribute__((ext_vector_type(4)));
typedef ushort  u16x8  __attribute__((ext_vector_type(8)));

__device__ __forceinline__ ushort f2bf(float f) {   // RNE f32 -> bf16
    unsigned u = __builtin_bit_cast(unsigned, f);
    return (ushort)((u + 0x7fffu + ((u >> 16) & 1u)) >> 16);
}

__device__ __forceinline__ bf16x8 ld_bf8(const ushort* p) {
    return __builtin_bit_cast(bf16x8, *reinterpret_cast<const uint4*>(p));
}

// ---------------------------------------------------------------------------
// K1: [h_i | h_j] (16384 x 128) = h[:, :256] (ld=320) @ [a_link | b_link]
//     BM=32, BN=128, BK=32; 256 threads; 2x8 acc; bf16 output.
// ---------------------------------------------------------------------------
__global__ __launch_bounds__(256) void k1_proj(const float* __restrict__ h,
                                               const float* __restrict__ al,
                                               const float* __restrict__ bl,
                                               ushort* __restrict__ hi,
                                               ushort* __restrict__ hj) {
    __shared__ float a_lds[32][36];    // 32 rows x 32 k
    __shared__ float w_lds[32][132];   // 32 k x 128 cols

    const int t  = threadIdx.x;
    const int m0 = blockIdx.x * 32;
    const int ty = t >> 4, tx = t & 15;   // 16 x 16 thread grid

    float acc[2][8];
#pragma unroll
    for (int i = 0; i < 2; ++i)
#pragma unroll
        for (int j = 0; j < 8; ++j) acc[i][j] = 0.f;

    for (int k0 = 0; k0 < FOBS; k0 += 32) {
        __syncthreads();
        // stage A tile: 32x32 f32 = 256 float4, 1 per thread
        {
            int r = t >> 3, q = t & 7;
            float4 v = *reinterpret_cast<const float4*>(
                &h[(size_t)(m0 + r) * FDIM + k0 + q * 4]);
            *reinterpret_cast<float4*>(&a_lds[r][q * 4]) = v;
        }
        // stage W tile: 32x128 f32 = 1024 float4, 4 per thread
#pragma unroll
        for (int s = 0; s < 4; ++s) {
            int id = t + s * 256;
            int kk = id >> 5, ch = id & 31;
            const float* src = (ch < 16) ? &al[(size_t)(k0 + kk) * 64 + ch * 4]
                                         : &bl[(size_t)(k0 + kk) * 64 + (ch - 16) * 4];
            float4 v = *reinterpret_cast<const float4*>(src);
            *reinterpret_cast<float4*>(&w_lds[kk][ch * 4]) = v;
        }
        __syncthreads();

#pragma unroll
        for (int kk = 0; kk < 32; kk += 4) {
            float a_k[2][4];
#pragma unroll
            for (int i = 0; i < 2; ++i) {
                float4 v = *reinterpret_cast<const float4*>(&a_lds[ty * 2 + i][kk]);
                a_k[i][0] = v.x; a_k[i][1] = v.y; a_k[i][2] = v.z; a_k[i][3] = v.w;
            }
#pragma unroll
            for (int q = 0; q < 4; ++q) {
                float4 w0 = *reinterpret_cast<const float4*>(&w_lds[kk + q][tx * 8]);
                float4 w1 = *reinterpret_cast<const float4*>(&w_lds[kk + q][tx * 8 + 4]);
                float wv[8] = {w0.x, w0.y, w0.z, w0.w, w1.x, w1.y, w1.z, w1.w};
#pragma unroll
                for (int i = 0; i < 2; ++i) {
                    float a = a_k[i][q];
#pragma unroll
                    for (int j = 0; j < 8; ++j)
                        acc[i][j] = fmaf(a, wv[j], acc[i][j]);
                }
            }
        }
    }

    // epilogue: cols 0..63 -> hi, 64..127 -> hj, packed bf16 (8 per thread-row)
    const int c = tx * 8;
    ushort* dst = (c < 64) ? (hi + c) : (hj + (c - 64));
#pragma unroll
    for (int i = 0; i < 2; ++i) {
        size_t row = (size_t)(m0 + ty * 2 + i);
        u16x8 v;
#pragma unroll
        for (int j = 0; j < 8; ++j) v[j] = f2bf(acc[i][j]);
        *reinterpret_cast<u16x8*>(&dst[row * 64]) = v;
    }
}

// ---------------------------------------------------------------------------
// K2 (MFMA): per (b, 64x64 tile): logits = hi_tile @ hj_tile^T / 8.
//   4 waves, wave w owns rows [16w,16w+16). No LDS for operands.
//   A-frag lane l: hi[i0+16w+(l&15)][(l>>4)*8 + 32*ks ..+8]   (16B load)
//   B-frag lane l: hj[j0+16jt+(l&15)][(l>>4)*8 + 32*ks ..+8]  (16B load)
//   D lane l reg r: row=(l>>4)*4+r, col=l&15   (m89-verified layout)
//   Epilogue fused: A = (x>0) | diag, logp = -log(1+exp(-|x|)) off-diag.
// ---------------------------------------------------------------------------
__global__ __launch_bounds__(256, 4) void k2_mfma(const ushort* __restrict__ hi,
                                                  const ushort* __restrict__ hj,
                                                  float* __restrict__ Aout,
                                                  float* __restrict__ partials) {
    __shared__ float red[4];
    const int t  = threadIdx.x;
    const int w  = t >> 6;
    const int l  = t & 63;
    const int lr = l & 15;
    const int lg = l >> 4;
    const int jt = blockIdx.x, it = blockIdx.y, b = blockIdx.z;
    const int i0 = it * 64, j0 = jt * 64;

    const ushort* hib = hi + ((size_t)b * NPTS + i0) * DK;
    const ushort* hjb = hj + ((size_t)b * NPTS + j0) * DK;

    // issue all operand loads up front (10 x 16B per lane)
    bf16x8 afr[2];
#pragma unroll
    for (int ks = 0; ks < 2; ++ks)
        afr[ks] = ld_bf8(&hib[(size_t)(16 * w + lr) * DK + ks * 32 + lg * 8]);

    bf16x8 bfr[4][2];
#pragma unroll
    for (int jtt = 0; jtt < 4; ++jtt)
#pragma unroll
        for (int ks = 0; ks < 2; ++ks)
            bfr[jtt][ks] = ld_bf8(&hjb[(size_t)(16 * jtt + lr) * DK + ks * 32 + lg * 8]);

    f32x4 acc[4];
#pragma unroll
    for (int jtt = 0; jtt < 4; ++jtt) acc[jtt] = (f32x4){0.f, 0.f, 0.f, 0.f};

#pragma unroll
    for (int ks = 0; ks < 2; ++ks)
#pragma unroll
        for (int jtt = 0; jtt < 4; ++jtt)
            acc[jtt] = __builtin_amdgcn_mfma_f32_16x16x32_bf16(
                afr[ks], bfr[jtt][ks], acc[jtt], 0, 0, 0);

    // fused epilogue
    float lsum = 0.f;
    const int drow0 = i0 + 16 * w + lg * 4;
#pragma unroll
    for (int jtt = 0; jtt < 4; ++jtt) {
        const int col = j0 + 16 * jtt + lr;
#pragma unroll
        for (int r = 0; r < 4; ++r) {
            const int row = drow0 + r;
            float x  = acc[jtt][r] * 0.125f;   // / sqrt(64), tau = 1
            float ax = fabsf(x);
            float nl = __logf(1.0f + __expf(-ax));   // -log(sel), sel>=0.5
            bool diag = (row == col);
            float ov = (diag || x > 0.f) ? 1.f : 0.f;
            if (!diag) lsum -= nl;
            Aout[((size_t)b * NPTS + row) * NPTS + col] = ov;
        }
    }

    // deterministic block reduction of lsum
#pragma unroll
    for (int off = 32; off > 0; off >>= 1) lsum += __shfl_down(lsum, off);
    if (l == 0) red[w] = lsum;
    __syncthreads();
    if (t == 0) {
        float s = (red[0] + red[1]) + (red[2] + red[3]);
        partials[(size_t)b * 64 + it * 8 + jt] = s;
    }
}

// ---------------------------------------------------------------------------
// K3: probs[b] = sum of 64 tile partials (deterministic wave reduction)
// ---------------------------------------------------------------------------
__global__ __launch_bounds__(64) void k3_reduce(const float* __restrict__ partials,
                                                float* __restrict__ probs) {
    int b = blockIdx.x;
    float s = partials[(size_t)b * 64 + threadIdx.x];
#pragma unroll
    for (int off = 32; off > 0; off >>= 1) s += __shfl_down(s, off);
    if (threadIdx.x == 0) probs[b] = s;
}

extern "C" void kernel_launch(void* const* d_in, const int* in_sizes, int n_in,
                              void* d_out, int out_size, void* d_ws, size_t ws_size,
                              hipStream_t stream) {
    const float* h  = (const float*)d_in[0];
    const float* al = (const float*)d_in[1];
    const float* bl = (const float*)d_in[2];
    float* out = (float*)d_out;

    ushort* hi      = (ushort*)d_ws;                      // 16384*64 bf16 (2 MB)
    ushort* hj      = hi + (size_t)MROWS * DK;            // 16384*64 bf16 (2 MB)
    float* partials = (float*)(hj + (size_t)MROWS * DK);  // 32*64 f32

    k1_proj<<<MROWS / 32, 256, 0, stream>>>(h, al, bl, hi, hj);

    dim3 g2(NPTS / 64, NPTS / 64, BATCH);
    k2_mfma<<<g2, 256, 0, stream>>>(hi, hj, out, partials);

    k3_reduce<<<BATCH, 64, 0, stream>>>(partials, out + A_ELEMS);
}

// Round 4
// 38.580 us; speedup vs baseline: 3.8746x; 1.1615x over previous
//
#include <hip/hip_runtime.h>
#include <math.h>

// Problem constants (fixed by setup_inputs)
//   h: (32, 512, 320) f32, a_link/b_link: (256, 64) f32, rollout: 1 (unused)
// Outputs: A_out (32,512,512) f32  then probs (32,) f32, concatenated.
#define BATCH   32
#define NPTS    512
#define FDIM    320
#define FOBS    256
#define DK      64
#define MROWS   (BATCH * NPTS)            // 16384
#define A_ELEMS ((size_t)BATCH * NPTS * NPTS)  // 8388608

typedef __bf16  bf16x8 __attribute__((ext_vector_type(8)));
typedef float   f32x4  __attribute__((ext_vector_type(4)));
typedef ushort  u16x8  __attribute__((ext_vector_type(8)));

__device__ __forceinline__ ushort f2bf(float f) {   // RNE f32 -> bf16
    unsigned u = __builtin_bit_cast(unsigned, f);
    return (ushort)((u + 0x7fffu + ((u >> 16) & 1u)) >> 16);
}

__device__ __forceinline__ bf16x8 ld_bf8(const ushort* p) {
    return __builtin_bit_cast(bf16x8, *reinterpret_cast<const uint4*>(p));
}

// ---------------------------------------------------------------------------
// K0: Wt[n][k] = bf16( n<64 ? a_link[k][n] : b_link[k][n-64] )   (128 x 256)
//     Tiny (32K elems); strided reads are L2-absorbed.
// ---------------------------------------------------------------------------
__global__ __launch_bounds__(256) void k0_wt(const float* __restrict__ al,
                                             const float* __restrict__ bl,
                                             ushort* __restrict__ wt) {
    const int n = blockIdx.x;            // 0..127
    const int k = threadIdx.x;           // 0..255
    const float* src = (n < 64) ? al : bl;
    const int nn = n & 63;
    wt[(size_t)n * FOBS + k] = f2bf(src[(size_t)k * DK + nn]);
}

// ---------------------------------------------------------------------------
// K1 (MFMA, no LDS): [hi|hj](16384x128) = h[:,:256] @ W, all bf16 MFMA.
//   BM=32 per block, 4 waves: wave w -> rows rb=bm0+16*(w&1), cols cb=64*(w>>1).
//   a-frag: lane l reads h[rb+(l&15)][ks*32+(l>>4)*8 ..+8] f32 -> cvt bf16x8.
//   b-frag: lane l reads Wt[cb+16*cf+(l&15)][ks*32+(l>>4)*8 ..+8] (16B, L2).
//   D lane l reg r: row=(l>>4)*4+r, col=l&15  (same layout as verified k2).
// ---------------------------------------------------------------------------
__global__ __launch_bounds__(256) void k1_mfma(const float* __restrict__ h,
                                               const ushort* __restrict__ wt,
                                               ushort* __restrict__ hi,
                                               ushort* __restrict__ hj) {
    const int t  = threadIdx.x;
    const int w  = t >> 6;
    const int l  = t & 63;
    const int lr = l & 15;
    const int lg = l >> 4;
    const int rb = blockIdx.x * 32 + 16 * (w & 1);
    const int cb = 64 * (w >> 1);        // 0 -> hi, 64 -> hj

    // a-frags: 8 k-steps, f32 loads converted in-register
    const float* hrow = h + (size_t)(rb + lr) * FDIM;
    bf16x8 afr[8];
#pragma unroll
    for (int ks = 0; ks < 8; ++ks) {
        const float* p = hrow + ks * 32 + lg * 8;
        float4 v0 = *reinterpret_cast<const float4*>(p);
        float4 v1 = *reinterpret_cast<const float4*>(p + 4);
        u16x8 u;
        u[0] = f2bf(v0.x); u[1] = f2bf(v0.y); u[2] = f2bf(v0.z); u[3] = f2bf(v0.w);
        u[4] = f2bf(v1.x); u[5] = f2bf(v1.y); u[6] = f2bf(v1.z); u[7] = f2bf(v1.w);
        afr[ks] = __builtin_bit_cast(bf16x8, u);
    }

    f32x4 acc[4];
#pragma unroll
    for (int cf = 0; cf < 4; ++cf) acc[cf] = (f32x4){0.f, 0.f, 0.f, 0.f};

#pragma unroll
    for (int ks = 0; ks < 8; ++ks) {
#pragma unroll
        for (int cf = 0; cf < 4; ++cf) {
            bf16x8 bfr = ld_bf8(&wt[(size_t)(cb + 16 * cf + lr) * FOBS + ks * 32 + lg * 8]);
            acc[cf] = __builtin_amdgcn_mfma_f32_16x16x32_bf16(afr[ks], bfr, acc[cf], 0, 0, 0);
        }
    }

    // epilogue: scatter bf16 (16 x 2B stores/lane; 32B segments, L2 assembles)
    ushort* dst = (cb == 0) ? hi : hj;
#pragma unroll
    for (int cf = 0; cf < 4; ++cf) {
        const int nn = 16 * cf + lr;
#pragma unroll
        for (int r = 0; r < 4; ++r) {
            const int m = rb + lg * 4 + r;
            dst[(size_t)m * DK + nn] = f2bf(acc[cf][r]);
        }
    }
}

// ---------------------------------------------------------------------------
// K2 (MFMA): per (b, 64x64 tile): logits = hi_tile @ hj_tile^T / 8.
//   1D grid, XCD-swizzled: id&7 = XCD owns 4 whole batches (512 KB << 4MB L2).
//   Fused epilogue: A = (x>0) | diag (nontemporal), logp partial per tile.
// ---------------------------------------------------------------------------
__global__ __launch_bounds__(256, 4) void k2_mfma(const ushort* __restrict__ hi,
                                                  const ushort* __restrict__ hj,
                                                  float* __restrict__ Aout,
                                                  float* __restrict__ partials) {
    __shared__ float red[4];
    const int id  = blockIdx.x;
    const int sub = id >> 3;
    const int b   = (id & 7) * 4 + (sub >> 6);
    const int it  = (sub >> 3) & 7;
    const int jt  = sub & 7;

    const int t  = threadIdx.x;
    const int w  = t >> 6;
    const int l  = t & 63;
    const int lr = l & 15;
    const int lg = l >> 4;
    const int i0 = it * 64, j0 = jt * 64;

    const ushort* hib = hi + ((size_t)b * NPTS + i0) * DK;
    const ushort* hjb = hj + ((size_t)b * NPTS + j0) * DK;

    // issue all operand loads up front (10 x 16B per lane)
    bf16x8 afr[2];
#pragma unroll
    for (int ks = 0; ks < 2; ++ks)
        afr[ks] = ld_bf8(&hib[(size_t)(16 * w + lr) * DK + ks * 32 + lg * 8]);

    bf16x8 bfr[4][2];
#pragma unroll
    for (int jtt = 0; jtt < 4; ++jtt)
#pragma unroll
        for (int ks = 0; ks < 2; ++ks)
            bfr[jtt][ks] = ld_bf8(&hjb[(size_t)(16 * jtt + lr) * DK + ks * 32 + lg * 8]);

    f32x4 acc[4];
#pragma unroll
    for (int jtt = 0; jtt < 4; ++jtt) acc[jtt] = (f32x4){0.f, 0.f, 0.f, 0.f};

#pragma unroll
    for (int ks = 0; ks < 2; ++ks)
#pragma unroll
        for (int jtt = 0; jtt < 4; ++jtt)
            acc[jtt] = __builtin_amdgcn_mfma_f32_16x16x32_bf16(
                afr[ks], bfr[jtt][ks], acc[jtt], 0, 0, 0);

    // fused epilogue
    float lsum = 0.f;
    const int drow0 = i0 + 16 * w + lg * 4;
#pragma unroll
    for (int jtt = 0; jtt < 4; ++jtt) {
        const int col = j0 + 16 * jtt + lr;
#pragma unroll
        for (int r = 0; r < 4; ++r) {
            const int row = drow0 + r;
            float x  = acc[jtt][r] * 0.125f;   // / sqrt(64), tau = 1
            float ax = fabsf(x);
            float nl = __logf(1.0f + __expf(-ax));   // -log(sel), sel>=0.5
            bool diag = (row == col);
            float ov = (diag || x > 0.f) ? 1.f : 0.f;
            if (!diag) lsum -= nl;
            __builtin_nontemporal_store(ov, &Aout[((size_t)b * NPTS + row) * NPTS + col]);
        }
    }

    // deterministic block reduction of lsum
#pragma unroll
    for (int off = 32; off > 0; off >>= 1) lsum += __shfl_down(lsum, off);
    if (l == 0) red[w] = lsum;
    __syncthreads();
    if (t == 0) {
        float s = (red[0] + red[1]) + (red[2] + red[3]);
        partials[(size_t)b * 64 + it * 8 + jt] = s;
    }
}

// ---------------------------------------------------------------------------
// K3: probs[b] = sum of 64 tile partials (deterministic wave reduction)
// ---------------------------------------------------------------------------
__global__ __launch_bounds__(64) void k3_reduce(const float* __restrict__ partials,
                                                float* __restrict__ probs) {
    int b = blockIdx.x;
    float s = partials[(size_t)b * 64 + threadIdx.x];
#pragma unroll
    for (int off = 32; off > 0; off >>= 1) s += __shfl_down(s, off);
    if (threadIdx.x == 0) probs[b] = s;
}

extern "C" void kernel_launch(void* const* d_in, const int* in_sizes, int n_in,
                              void* d_out, int out_size, void* d_ws, size_t ws_size,
                              hipStream_t stream) {
    const float* h  = (const float*)d_in[0];
    const float* al = (const float*)d_in[1];
    const float* bl = (const float*)d_in[2];
    float* out = (float*)d_out;

    ushort* hi      = (ushort*)d_ws;                      // 16384*64 bf16 (2 MB)
    ushort* hj      = hi + (size_t)MROWS * DK;            // 16384*64 bf16 (2 MB)
    ushort* wt      = hj + (size_t)MROWS * DK;            // 128*256 bf16 (64 KB)
    float* partials = (float*)(wt + 128 * FOBS);          // 32*64 f32

    k0_wt<<<128, 256, 0, stream>>>(al, bl, wt);

    k1_mfma<<<MROWS / 32, 256, 0, stream>>>(h, wt, hi, hj);

    k2_mfma<<<(NPTS / 64) * (NPTS / 64) * BATCH, 256, 0, stream>>>(hi, hj, out, partials);

    k3_reduce<<<BATCH, 64, 0, stream>>>(partials, out + A_ELEMS);
}